// Round 11
// baseline (168.990 us; speedup 1.0000x reference)
//
#include <hip/hip_runtime.h>
#include <hip/hip_bf16.h>

#define NPOS 6272          // 8*28*28
#define NT   98            // NPOS/64
#define CIN  256
#define CR   32
#define BATCH 2
// QSCALE * log2(e): scores come out in log2 units -> softmax uses raw exp2
#define QS2  0.25503371989518595f
#define PPITCH 72          // P^T LDS row pitch (shorts): 144B, 16B-aligned

typedef short bf16x8s __attribute__((ext_vector_type(8)));  // 8 x 16b = 4 VGPR
typedef short short4v __attribute__((ext_vector_type(4)));  // 4 x 16b = 8B
typedef _Float16 f16x8 __attribute__((ext_vector_type(8))); // MFMA f16 A/B frag
typedef float f32x4   __attribute__((ext_vector_type(4)));
typedef unsigned short ushort_t;

__device__ __forceinline__ ushort_t f2bf(float f) {        // RNE fp32->bf16
    unsigned u = __builtin_bit_cast(unsigned, f);
    u += 0x7fff + ((u >> 16) & 1);
    return (ushort_t)(u >> 16);
}
__device__ __forceinline__ float bf2f(ushort_t h) {
    return __builtin_bit_cast(float, (unsigned)h << 16);
}
// fp32 -> fp16 bit pattern (compiler-lowered v_cvt_f16_f32, RNE)
__device__ __forceinline__ ushort_t f2h(float f) {
    return __builtin_bit_cast(ushort_t, (_Float16)f);
}

// ---------------------------------------------------------------------------
// Kernel 1 (R11): FUSED Q/K/V projection — single pass over x (was 3 passes
// via grid z=3; x re-read 3x = ~38MB HBM). 24 accumulators/wave; c-unroll 2
// keeps wave-uniform w s-loads <= 48 in flight (the prior session's big-batch
// SGPR failure used unroll 8). Same total FLOPs, 1/3 the x traffic.
// grid (NT, B); block 256 = 4 waves; wave g computes rows 8g..8g+7 of all 3.
// ---------------------------------------------------------------------------
__global__ __launch_bounds__(256) void qkv_kernel(
    const float* __restrict__ x, const float* __restrict__ qw,
    const float* __restrict__ kw, const float* __restrict__ vw,
    ushort_t* __restrict__ Qf, ushort_t* __restrict__ Kf,
    ushort_t* __restrict__ Vt)
{
    const int b   = blockIdx.y;
    const int nl  = threadIdx.x & 63;
    const int n   = blockIdx.x * 64 + nl;
    const int g   = __builtin_amdgcn_readfirstlane(threadIdx.x >> 6); // 0..3
    const float* xb = x + (size_t)b * CIN * NPOS + n;

    float aq[8], ak[8], av[8];
#pragma unroll
    for (int i = 0; i < 8; ++i) { aq[i] = 0.f; ak[i] = 0.f; av[i] = 0.f; }
#pragma unroll 2
    for (int c = 0; c < CIN; ++c) {
        float xv = xb[(size_t)c * NPOS];
#pragma unroll
        for (int i = 0; i < 8; ++i) {
            aq[i] += qw[(g * 8 + i) * CIN + c] * xv;   // wave-uniform -> smem
            ak[i] += kw[(g * 8 + i) * CIN + c] * xv;
            av[i] += vw[(g * 8 + i) * CIN + c] * xv;
        }
    }
    bf16x8s fq, fk;
#pragma unroll
    for (int i = 0; i < 8; ++i) {
        fq[i] = (short)f2h(aq[i] * QS2);         // fold softmax scale into Q
        fk[i] = (short)f2h(ak[i]);
    }
    size_t off = ((size_t)b * NPOS + n) * CR + g * 8;
    *(bf16x8s*)(Qf + off) = fq;
    *(bf16x8s*)(Kf + off) = fk;
#pragma unroll
    for (int i = 0; i < 8; ++i)                  // V -> transposed [32][N], f16
        Vt[((size_t)b * CR + g * 8 + i) * NPOS + n] = f2h(av[i]);
}

// ---------------------------------------------------------------------------
// Kernel 2: MFMA flash attention (R9-exact: KVBLK=64, fp16 single precision).
// R10's KVBLK=128 was spill-free but ~+1.7us -> reverted. R9 mechanism: one
// f16 MFMA per fragment (no hi/lo chain), 8 loads/tile, parity double-buffer.
// grid (98, S, B); block 128 = 2 independent waves (private pbuf halves).
// ---------------------------------------------------------------------------
__device__ __forceinline__ void load_tile(
    const ushort_t* __restrict__ Kfb, const ushort_t* __restrict__ Vtb,
    int j0, int col, int quad, bf16x8s* kf, bf16x8s* vb)
{
#pragma unroll
    for (int f = 0; f < 4; ++f)
        kf[f] = *(const bf16x8s*)(Kfb + (size_t)(j0 + f * 16 + col) * CR + quad * 8);
#pragma unroll
    for (int k2 = 0; k2 < 2; ++k2)
#pragma unroll
        for (int c = 0; c < 2; ++c)
            vb[k2 * 2 + c] = *(const bf16x8s*)(
                Vtb + (size_t)(c * 16 + col) * NPOS + j0 + k2 * 32 + quad * 8);
}

__device__ __forceinline__ void compute_tile(
    const bf16x8s* kf, const bf16x8s* vb, const bf16x8s* qb,
    f32x4 (&oc)[2][2], float (&m_)[2], float (&l_)[2],
    ushort_t* pb, int col, int quad)
{
    f32x4 z4 = {0.f, 0.f, 0.f, 0.f};
#pragma unroll
    for (int h = 0; h < 2; ++h) {
        f32x4 sc[4];                             // S^T: key=f*16+quad*4+r, q=col
#pragma unroll
        for (int f = 0; f < 4; ++f)
            sc[f] = __builtin_amdgcn_mfma_f32_16x16x32_f16(
                __builtin_bit_cast(f16x8, kf[f]),
                __builtin_bit_cast(f16x8, qb[h]), z4, 0, 0, 0);
        // 16 -> 1 max as triples: v_max3 chains
        float a0 = fmaxf(fmaxf(sc[0][0], sc[0][1]), sc[0][2]);
        float a1 = fmaxf(fmaxf(sc[0][3], sc[1][0]), sc[1][1]);
        float a2 = fmaxf(fmaxf(sc[1][2], sc[1][3]), sc[2][0]);
        float a3 = fmaxf(fmaxf(sc[2][1], sc[2][2]), sc[2][3]);
        float a4 = fmaxf(fmaxf(sc[3][0], sc[3][1]), sc[3][2]);
        float b0 = fmaxf(fmaxf(a0, a1), a2);
        float b1 = fmaxf(fmaxf(a3, a4), sc[3][3]);
        float v  = fmaxf(b0, b1);
        v = fmaxf(v, __shfl_xor(v, 16));
        v = fmaxf(v, __shfl_xor(v, 32));
        float mo = m_[h];
        float mn = mo;
        if (!__all(v <= mo)) {                   // max grew for some q: rescale
            mn = fmaxf(mo, v);
            float al = __builtin_amdgcn_exp2f(mo - mn);  // lane-uniform per q
            m_[h] = mn;
            l_[h] *= al;
#pragma unroll
            for (int r = 0; r < 4; ++r) { oc[h][0][r] *= al; oc[h][1][r] *= al; }
        }
        float lsum = 0.f;
#pragma unroll
        for (int f = 0; f < 4; ++f) {
            float p0 = __builtin_amdgcn_exp2f(sc[f][0] - mn);
            float p1 = __builtin_amdgcn_exp2f(sc[f][1] - mn);
            float p2 = __builtin_amdgcn_exp2f(sc[f][2] - mn);
            float p3 = __builtin_amdgcn_exp2f(sc[f][3] - mn);
            lsum += (p0 + p1) + (p2 + p3);
            short4v pk;
            pk[0] = (short)f2h(p0);
            pk[1] = (short)f2h(p1);
            pk[2] = (short)f2h(p2);
            pk[3] = (short)f2h(p3);
            *(short4v*)(&pb[h * 16 * PPITCH + col * PPITCH + f * 16 + quad * 4]) = pk;
        }
        l_[h] += lsum;
    }
    // PV: O^T += V^T · P^T (same-wave DS ops in-order; same-type LDS accesses
    // alias -> compiler preserves store->load order, no fence needed)
#pragma unroll
    for (int h = 0; h < 2; ++h) {
#pragma unroll
        for (int k2 = 0; k2 < 2; ++k2) {
            bf16x8s pbo = *(const bf16x8s*)(
                &pb[h * 16 * PPITCH + col * PPITCH + k2 * 32 + quad * 8]);
            oc[h][0] = __builtin_amdgcn_mfma_f32_16x16x32_f16(
                __builtin_bit_cast(f16x8, vb[k2 * 2 + 0]),
                __builtin_bit_cast(f16x8, pbo), oc[h][0], 0, 0, 0);
            oc[h][1] = __builtin_amdgcn_mfma_f32_16x16x32_f16(
                __builtin_bit_cast(f16x8, vb[k2 * 2 + 1]),
                __builtin_bit_cast(f16x8, pbo), oc[h][1], 0, 0, 0);
        }
    }
}

template <int ITERS>
__global__ __launch_bounds__(128, 2) void attn_kernel(
    const ushort_t* __restrict__ Qf, const ushort_t* __restrict__ Kf,
    const ushort_t* __restrict__ Vt, ushort_t* __restrict__ Opart,
    float* __restrict__ Mp, float* __restrict__ Lp)
{
    __shared__ __align__(16) ushort_t pbuf[2 * 2 * 16 * PPITCH];

    const int lane = threadIdx.x & 63;
    const int wv   = threadIdx.x >> 6;           // 0..1
    const int col  = lane & 15;                  // query (local)
    const int quad = lane >> 4;                  // 0..3
    const int b    = blockIdx.z;
    const int s    = blockIdx.y;
    const int qw0  = blockIdx.x * 64 + wv * 32;
    ushort_t* pb   = &pbuf[wv * 2 * 16 * PPITCH];

    const ushort_t* Qfb = Qf + (size_t)b * NPOS * CR;
    const ushort_t* Kfb = Kf + (size_t)b * NPOS * CR;
    const ushort_t* Vtb = Vt + (size_t)b * CR * NPOS;

    bf16x8s qb[2];                               // Q as B-operand (fp16 bits)
    qb[0] = *(const bf16x8s*)(Qfb + (size_t)(qw0 + col) * CR + quad * 8);
    qb[1] = *(const bf16x8s*)(Qfb + (size_t)(qw0 + 16 + col) * CR + quad * 8);

    f32x4 oc[2][2];
#pragma unroll
    for (int h = 0; h < 2; ++h)
#pragma unroll
        for (int c = 0; c < 2; ++c)
#pragma unroll
            for (int r = 0; r < 4; ++r) oc[h][c][r] = 0.f;
    float m_[2] = { -1e30f, -1e30f };
    float l_[2] = { 0.f, 0.f };

    if constexpr (ITERS <= 14) {
        // Software pipeline, fully unrolled; parity-indexed double buffer
        // (compile-time indices -> SROA, no rotation movs, no scratch).
        bf16x8s kf2[2][4], vb2[2][4];
        load_tile(Kfb, Vtb, s * ITERS * 64, col, quad, kf2[0], vb2[0]);
#pragma unroll
        for (int it = 0; it < ITERS; ++it) {
            const int cur = it & 1;
            if (it + 1 < ITERS)
                load_tile(Kfb, Vtb, (s * ITERS + it + 1) * 64, col, quad,
                          kf2[cur ^ 1], vb2[cur ^ 1]);
            compute_tile(kf2[cur], vb2[cur], qb, oc, m_, l_, pb, col, quad);
        }
    } else {                                     // fallback: plain loop
        for (int it = 0; it < ITERS; ++it) {
            bf16x8s kf[4], vb[4];
            load_tile(Kfb, Vtb, (s * ITERS + it) * 64, col, quad, kf, vb);
            compute_tile(kf, vb, qb, oc, m_, l_, pb, col, quad);
        }
    }

    // Finish l: reduce per-lane partials across quads (same q = same col).
#pragma unroll
    for (int h = 0; h < 2; ++h) {
        float l = l_[h];
        l += __shfl_xor(l, 16);
        l += __shfl_xor(l, 32);
        l_[h] = l;
    }

    const size_t sb = (size_t)(s * BATCH + b);
    ushort_t* Ob = Opart + sb * CR * NPOS;
#pragma unroll
    for (int h = 0; h < 2; ++h)
#pragma unroll
        for (int c = 0; c < 2; ++c)
#pragma unroll
            for (int r = 0; r < 4; ++r) {
                int ch = c * 16 + quad * 4 + r;
                Ob[(size_t)ch * NPOS + qw0 + h * 16 + col] = f2bf(oc[h][c][r]);
            }
    if (quad == 0) {                             // 16 lanes own the 16 q's
#pragma unroll
        for (int h = 0; h < 2; ++h) {
            Mp[sb * NPOS + qw0 + h * 16 + col] = m_[h];
            Lp[sb * NPOS + qw0 + h * 16 + col] = l_[h];
        }
    }
}

// ---------------------------------------------------------------------------
// Kernel 3: merge key-splits (log-sum-exp) -> Omrg [B][32][N] fp32.
// (R4-proven: Mp cached in registers) grid (NT, B, 8): wave g, ch r=z*4+g.
// ---------------------------------------------------------------------------
template <int S_>
__global__ __launch_bounds__(256) void merge_kernel(
    const ushort_t* __restrict__ Opart, const float* __restrict__ Mp,
    const float* __restrict__ Lp, float* __restrict__ Omrg)
{
    const int b  = blockIdx.y;
    const int z  = blockIdx.z;
    const int nl = threadIdx.x & 63;
    const int n  = blockIdx.x * 64 + nl;
    const int g  = __builtin_amdgcn_readfirstlane(threadIdx.x >> 6);
    const int r  = z * 4 + g;

    float mv[S_];
    float mg = -1e30f;
#pragma unroll
    for (int s = 0; s < S_; ++s) {
        mv[s] = Mp[(size_t)(s * BATCH + b) * NPOS + n];
        mg = fmaxf(mg, mv[s]);
    }
    float lg = 0.f, acc = 0.f;
#pragma unroll
    for (int s = 0; s < S_; ++s) {
        size_t sb = (size_t)(s * BATCH + b);
        float w = __builtin_amdgcn_exp2f(mv[s] - mg);
        lg  += w * Lp[sb * NPOS + n];
        acc += w * bf2f(Opart[(sb * CR + r) * NPOS + n]);   // coalesced
    }
    Omrg[((size_t)b * CR + r) * NPOS + n] = acc / lg;
}

// ---------------------------------------------------------------------------
// Kernel 4 (R11): output projection + residual, z=4 (was 8): halves the
// redundant Omrg re-reads (12.8 -> 6.4 MB). Wave g handles 16 channels.
// grid (NT, B, 4), block 256.
// ---------------------------------------------------------------------------
__global__ __launch_bounds__(256) void proj_kernel(
    const float* __restrict__ Omrg, const float* __restrict__ ow,
    const float* __restrict__ x, float* __restrict__ y)
{
    const int b  = blockIdx.y;
    const int z  = blockIdx.z;
    const int nl = threadIdx.x & 63;
    const int n  = blockIdx.x * 64 + nl;
    const int g  = __builtin_amdgcn_readfirstlane(threadIdx.x >> 6);

    float o[CR];
#pragma unroll
    for (int r = 0; r < CR; ++r)
        o[r] = Omrg[((size_t)b * CR + r) * NPOS + n];

    const float* xb = x + (size_t)b * CIN * NPOS + n;
    float*       yb = y + (size_t)b * CIN * NPOS + n;
    const int c0 = z * 64 + g * 16;
#pragma unroll
    for (int cc = 0; cc < 16; ++cc) {
        int c = c0 + cc;                          // wave-uniform
        float acc = xb[(size_t)c * NPOS];
#pragma unroll
        for (int r = 0; r < CR; ++r) acc += ow[c * CR + r] * o[r];
        yb[(size_t)c * NPOS] = acc;
    }
}

// ---------------------------------------------------------------------------
extern "C" void kernel_launch(void* const* d_in, const int* in_sizes, int n_in,
                              void* d_out, int out_size, void* d_ws, size_t ws_size,
                              hipStream_t stream)
{
    const float* x  = (const float*)d_in[0];
    const float* qw = (const float*)d_in[1];
    const float* kw = (const float*)d_in[2];
    const float* vw = (const float*)d_in[3];
    const float* ow = (const float*)d_in[4];
    float* out = (float*)d_out;

    const size_t qkvN = (size_t)BATCH * CR * NPOS;   // 401,408 elements
    // S must divide 98 (=6272/64). S=7: halved Opart/M/L traffic (proven);
    // attn ITERS=14 stays on the fully-pipelined path.
    const int s_cand[4] = {7, 14, 2, 1};
    int S = 1;
    for (int i = 0; i < 4; ++i) {
        int Sc = s_cand[i];
        size_t need = 3 * qkvN * sizeof(ushort_t)            // Qf,Kf,Vt
                    + qkvN * sizeof(float)                   // Omrg
                    + (size_t)Sc * qkvN * sizeof(ushort_t)   // Opart
                    + 2 * (size_t)Sc * BATCH * NPOS * sizeof(float); // M,L
        if (need <= ws_size) { S = Sc; break; }
    }
    ushort_t* Qf = (ushort_t*)d_ws;
    ushort_t* Kf = Qf + qkvN;
    ushort_t* Vt = Kf + qkvN;
    float* Omrg  = (float*)(Vt + qkvN);
    ushort_t* Op = (ushort_t*)(Omrg + qkvN);
    float* Mp    = (float*)(Op + (size_t)S * qkvN);
    float* Lp    = Mp + (size_t)S * BATCH * NPOS;

    qkv_kernel<<<dim3(NT, BATCH), 256, 0, stream>>>(x, qw, kw, vw, Qf, Kf, Vt);
    dim3 ag(NT, S, BATCH);
    switch (S) {
        case 14: attn_kernel<7> <<<ag, 128, 0, stream>>>(Qf, Kf, Vt, Op, Mp, Lp); break;
        case 7:  attn_kernel<14><<<ag, 128, 0, stream>>>(Qf, Kf, Vt, Op, Mp, Lp); break;
        case 2:  attn_kernel<49><<<ag, 128, 0, stream>>>(Qf, Kf, Vt, Op, Mp, Lp); break;
        default: attn_kernel<98><<<ag, 128, 0, stream>>>(Qf, Kf, Vt, Op, Mp, Lp); break;
    }
    dim3 mg(NT, BATCH, 8);
    switch (S) {
        case 14: merge_kernel<14><<<mg, 256, 0, stream>>>(Op, Mp, Lp, Omrg); break;
        case 7:  merge_kernel<7> <<<mg, 256, 0, stream>>>(Op, Mp, Lp, Omrg); break;
        case 2:  merge_kernel<2> <<<mg, 256, 0, stream>>>(Op, Mp, Lp, Omrg); break;
        default: merge_kernel<1> <<<mg, 256, 0, stream>>>(Op, Mp, Lp, Omrg); break;
    }
    proj_kernel<<<dim3(NT, BATCH, 4), 256, 0, stream>>>(Omrg, ow, x, out);
}

// Round 12
// 134.765 us; speedup vs baseline: 1.2540x; 1.2540x over previous
//
#include <hip/hip_runtime.h>
#include <hip/hip_bf16.h>

#define NPOS 6272          // 8*28*28
#define NT   98            // NPOS/64
#define CIN  256
#define CR   32
#define BATCH 2
// QSCALE * log2(e): scores come out in log2 units -> softmax uses raw exp2
#define QS2  0.25503371989518595f
#define PPITCH 72          // P^T LDS row pitch (shorts): 144B, 16B-aligned

typedef short bf16x8s __attribute__((ext_vector_type(8)));  // 8 x 16b = 4 VGPR
typedef short short4v __attribute__((ext_vector_type(4)));  // 4 x 16b = 8B
typedef _Float16 f16x8 __attribute__((ext_vector_type(8))); // MFMA f16 A/B frag
typedef float f32x4   __attribute__((ext_vector_type(4)));
typedef unsigned short ushort_t;

__device__ __forceinline__ ushort_t f2bf(float f) {        // RNE fp32->bf16
    unsigned u = __builtin_bit_cast(unsigned, f);
    u += 0x7fff + ((u >> 16) & 1);
    return (ushort_t)(u >> 16);
}
__device__ __forceinline__ float bf2f(ushort_t h) {
    return __builtin_bit_cast(float, (unsigned)h << 16);
}
// fp32 -> fp16 bit pattern (compiler-lowered v_cvt_f16_f32, RNE)
__device__ __forceinline__ ushort_t f2h(float f) {
    return __builtin_bit_cast(ushort_t, (_Float16)f);
}

// ---------------------------------------------------------------------------
// Kernel 1: Q/K/V projections -> SINGLE fp16 arrays (R9-proven split form).
// R11's fused single-pass version spilled its 24 accumulators to scratch
// (VGPR_Count=16, 12x slowdown) -> reverted to 8 acc / unroll 8 / z=3.
// grid (NT, B, 3); block 256 = 4 waves; wave g computes rows 8g..8g+7.
// ---------------------------------------------------------------------------
__global__ __launch_bounds__(256) void qkv_kernel(
    const float* __restrict__ x, const float* __restrict__ qw,
    const float* __restrict__ kw, const float* __restrict__ vw,
    ushort_t* __restrict__ Qf, ushort_t* __restrict__ Kf,
    ushort_t* __restrict__ Vt)
{
    const int b   = blockIdx.y;
    const int z   = blockIdx.z;
    const int nl  = threadIdx.x & 63;
    const int n   = blockIdx.x * 64 + nl;
    const int g   = __builtin_amdgcn_readfirstlane(threadIdx.x >> 6); // 0..3
    const float* w  = (z == 0) ? qw : (z == 1) ? kw : vw;
    const float* xb = x + (size_t)b * CIN * NPOS + n;

    float acc[8];
#pragma unroll
    for (int i = 0; i < 8; ++i) acc[i] = 0.f;
#pragma unroll 8
    for (int c = 0; c < CIN; ++c) {
        float xv = xb[(size_t)c * NPOS];
#pragma unroll
        for (int i = 0; i < 8; ++i)
            acc[i] += w[(g * 8 + i) * CIN + c] * xv;   // wave-uniform -> smem
    }
    if (z == 2) {                                // V -> transposed [32][N], f16
#pragma unroll
        for (int i = 0; i < 8; ++i)
            Vt[((size_t)b * CR + g * 8 + i) * NPOS + n] = f2h(acc[i]);
    } else {
        ushort_t* d = (z == 0) ? Qf : Kf;
        float s = (z == 0) ? QS2 : 1.0f;         // fold softmax scale into Q
        bf16x8s fh;
#pragma unroll
        for (int i = 0; i < 8; ++i)
            fh[i] = (short)f2h(acc[i] * s);
        *(bf16x8s*)(d + ((size_t)b * NPOS + n) * CR + g * 8) = fh;
    }
}

// ---------------------------------------------------------------------------
// Kernel 2: MFMA flash attention (R9-exact: KVBLK=64, fp16 single precision).
// One f16 MFMA per fragment (no hi/lo chain), 8 loads/tile, parity
// double-buffer (compile-time idx -> SROA), exact rescale-skip, max3 triples.
// grid (98, S, B); block 128 = 2 independent waves (private pbuf halves).
// ---------------------------------------------------------------------------
__device__ __forceinline__ void load_tile(
    const ushort_t* __restrict__ Kfb, const ushort_t* __restrict__ Vtb,
    int j0, int col, int quad, bf16x8s* kf, bf16x8s* vb)
{
#pragma unroll
    for (int f = 0; f < 4; ++f)
        kf[f] = *(const bf16x8s*)(Kfb + (size_t)(j0 + f * 16 + col) * CR + quad * 8);
#pragma unroll
    for (int k2 = 0; k2 < 2; ++k2)
#pragma unroll
        for (int c = 0; c < 2; ++c)
            vb[k2 * 2 + c] = *(const bf16x8s*)(
                Vtb + (size_t)(c * 16 + col) * NPOS + j0 + k2 * 32 + quad * 8);
}

__device__ __forceinline__ void compute_tile(
    const bf16x8s* kf, const bf16x8s* vb, const bf16x8s* qb,
    f32x4 (&oc)[2][2], float (&m_)[2], float (&l_)[2],
    ushort_t* pb, int col, int quad)
{
    f32x4 z4 = {0.f, 0.f, 0.f, 0.f};
#pragma unroll
    for (int h = 0; h < 2; ++h) {
        f32x4 sc[4];                             // S^T: key=f*16+quad*4+r, q=col
#pragma unroll
        for (int f = 0; f < 4; ++f)
            sc[f] = __builtin_amdgcn_mfma_f32_16x16x32_f16(
                __builtin_bit_cast(f16x8, kf[f]),
                __builtin_bit_cast(f16x8, qb[h]), z4, 0, 0, 0);
        // 16 -> 1 max as triples: v_max3 chains
        float a0 = fmaxf(fmaxf(sc[0][0], sc[0][1]), sc[0][2]);
        float a1 = fmaxf(fmaxf(sc[0][3], sc[1][0]), sc[1][1]);
        float a2 = fmaxf(fmaxf(sc[1][2], sc[1][3]), sc[2][0]);
        float a3 = fmaxf(fmaxf(sc[2][1], sc[2][2]), sc[2][3]);
        float a4 = fmaxf(fmaxf(sc[3][0], sc[3][1]), sc[3][2]);
        float b0 = fmaxf(fmaxf(a0, a1), a2);
        float b1 = fmaxf(fmaxf(a3, a4), sc[3][3]);
        float v  = fmaxf(b0, b1);
        v = fmaxf(v, __shfl_xor(v, 16));
        v = fmaxf(v, __shfl_xor(v, 32));
        float mo = m_[h];
        float mn = mo;
        if (!__all(v <= mo)) {                   // max grew for some q: rescale
            mn = fmaxf(mo, v);
            float al = __builtin_amdgcn_exp2f(mo - mn);  // lane-uniform per q
            m_[h] = mn;
            l_[h] *= al;
#pragma unroll
            for (int r = 0; r < 4; ++r) { oc[h][0][r] *= al; oc[h][1][r] *= al; }
        }
        float lsum = 0.f;
#pragma unroll
        for (int f = 0; f < 4; ++f) {
            float p0 = __builtin_amdgcn_exp2f(sc[f][0] - mn);
            float p1 = __builtin_amdgcn_exp2f(sc[f][1] - mn);
            float p2 = __builtin_amdgcn_exp2f(sc[f][2] - mn);
            float p3 = __builtin_amdgcn_exp2f(sc[f][3] - mn);
            lsum += (p0 + p1) + (p2 + p3);
            short4v pk;
            pk[0] = (short)f2h(p0);
            pk[1] = (short)f2h(p1);
            pk[2] = (short)f2h(p2);
            pk[3] = (short)f2h(p3);
            *(short4v*)(&pb[h * 16 * PPITCH + col * PPITCH + f * 16 + quad * 4]) = pk;
        }
        l_[h] += lsum;
    }
    // PV: O^T += V^T · P^T (same-wave DS ops in-order; same-type LDS accesses
    // alias -> compiler preserves store->load order, no fence needed)
#pragma unroll
    for (int h = 0; h < 2; ++h) {
#pragma unroll
        for (int k2 = 0; k2 < 2; ++k2) {
            bf16x8s pbo = *(const bf16x8s*)(
                &pb[h * 16 * PPITCH + col * PPITCH + k2 * 32 + quad * 8]);
            oc[h][0] = __builtin_amdgcn_mfma_f32_16x16x32_f16(
                __builtin_bit_cast(f16x8, vb[k2 * 2 + 0]),
                __builtin_bit_cast(f16x8, pbo), oc[h][0], 0, 0, 0);
            oc[h][1] = __builtin_amdgcn_mfma_f32_16x16x32_f16(
                __builtin_bit_cast(f16x8, vb[k2 * 2 + 1]),
                __builtin_bit_cast(f16x8, pbo), oc[h][1], 0, 0, 0);
        }
    }
}

template <int ITERS>
__global__ __launch_bounds__(128, 2) void attn_kernel(
    const ushort_t* __restrict__ Qf, const ushort_t* __restrict__ Kf,
    const ushort_t* __restrict__ Vt, ushort_t* __restrict__ Opart,
    float* __restrict__ Mp, float* __restrict__ Lp)
{
    __shared__ __align__(16) ushort_t pbuf[2 * 2 * 16 * PPITCH];

    const int lane = threadIdx.x & 63;
    const int wv   = threadIdx.x >> 6;           // 0..1
    const int col  = lane & 15;                  // query (local)
    const int quad = lane >> 4;                  // 0..3
    const int b    = blockIdx.z;
    const int s    = blockIdx.y;
    const int qw0  = blockIdx.x * 64 + wv * 32;
    ushort_t* pb   = &pbuf[wv * 2 * 16 * PPITCH];

    const ushort_t* Qfb = Qf + (size_t)b * NPOS * CR;
    const ushort_t* Kfb = Kf + (size_t)b * NPOS * CR;
    const ushort_t* Vtb = Vt + (size_t)b * CR * NPOS;

    bf16x8s qb[2];                               // Q as B-operand (fp16 bits)
    qb[0] = *(const bf16x8s*)(Qfb + (size_t)(qw0 + col) * CR + quad * 8);
    qb[1] = *(const bf16x8s*)(Qfb + (size_t)(qw0 + 16 + col) * CR + quad * 8);

    f32x4 oc[2][2];
#pragma unroll
    for (int h = 0; h < 2; ++h)
#pragma unroll
        for (int c = 0; c < 2; ++c)
#pragma unroll
            for (int r = 0; r < 4; ++r) oc[h][c][r] = 0.f;
    float m_[2] = { -1e30f, -1e30f };
    float l_[2] = { 0.f, 0.f };

    if constexpr (ITERS <= 14) {
        // Software pipeline, fully unrolled; parity-indexed double buffer
        // (compile-time indices -> SROA, no rotation movs, no scratch).
        bf16x8s kf2[2][4], vb2[2][4];
        load_tile(Kfb, Vtb, s * ITERS * 64, col, quad, kf2[0], vb2[0]);
#pragma unroll
        for (int it = 0; it < ITERS; ++it) {
            const int cur = it & 1;
            if (it + 1 < ITERS)
                load_tile(Kfb, Vtb, (s * ITERS + it + 1) * 64, col, quad,
                          kf2[cur ^ 1], vb2[cur ^ 1]);
            compute_tile(kf2[cur], vb2[cur], qb, oc, m_, l_, pb, col, quad);
        }
    } else {                                     // fallback: plain loop
        for (int it = 0; it < ITERS; ++it) {
            bf16x8s kf[4], vb[4];
            load_tile(Kfb, Vtb, (s * ITERS + it) * 64, col, quad, kf, vb);
            compute_tile(kf, vb, qb, oc, m_, l_, pb, col, quad);
        }
    }

    // Finish l: reduce per-lane partials across quads (same q = same col).
#pragma unroll
    for (int h = 0; h < 2; ++h) {
        float l = l_[h];
        l += __shfl_xor(l, 16);
        l += __shfl_xor(l, 32);
        l_[h] = l;
    }

    const size_t sb = (size_t)(s * BATCH + b);
    ushort_t* Ob = Opart + sb * CR * NPOS;
#pragma unroll
    for (int h = 0; h < 2; ++h)
#pragma unroll
        for (int c = 0; c < 2; ++c)
#pragma unroll
            for (int r = 0; r < 4; ++r) {
                int ch = c * 16 + quad * 4 + r;
                Ob[(size_t)ch * NPOS + qw0 + h * 16 + col] = f2bf(oc[h][c][r]);
            }
    if (quad == 0) {                             // 16 lanes own the 16 q's
#pragma unroll
        for (int h = 0; h < 2; ++h) {
            Mp[sb * NPOS + qw0 + h * 16 + col] = m_[h];
            Lp[sb * NPOS + qw0 + h * 16 + col] = l_[h];
        }
    }
}

// ---------------------------------------------------------------------------
// Kernel 3: merge key-splits (log-sum-exp) -> Omrg [B][32][N] fp32.
// (R4-proven: Mp cached in registers) grid (NT, B, 8): wave g, ch r=z*4+g.
// ---------------------------------------------------------------------------
template <int S_>
__global__ __launch_bounds__(256) void merge_kernel(
    const ushort_t* __restrict__ Opart, const float* __restrict__ Mp,
    const float* __restrict__ Lp, float* __restrict__ Omrg)
{
    const int b  = blockIdx.y;
    const int z  = blockIdx.z;
    const int nl = threadIdx.x & 63;
    const int n  = blockIdx.x * 64 + nl;
    const int g  = __builtin_amdgcn_readfirstlane(threadIdx.x >> 6);
    const int r  = z * 4 + g;

    float mv[S_];
    float mg = -1e30f;
#pragma unroll
    for (int s = 0; s < S_; ++s) {
        mv[s] = Mp[(size_t)(s * BATCH + b) * NPOS + n];
        mg = fmaxf(mg, mv[s]);
    }
    float lg = 0.f, acc = 0.f;
#pragma unroll
    for (int s = 0; s < S_; ++s) {
        size_t sb = (size_t)(s * BATCH + b);
        float w = __builtin_amdgcn_exp2f(mv[s] - mg);
        lg  += w * Lp[sb * NPOS + n];
        acc += w * bf2f(Opart[(sb * CR + r) * NPOS + n]);   // coalesced
    }
    Omrg[((size_t)b * CR + r) * NPOS + n] = acc / lg;
}

// ---------------------------------------------------------------------------
// Kernel 4: output projection + residual, z=4 (kept from R11: halves the
// redundant Omrg re-reads vs z=8; mechanism-sound, low risk).
// grid (NT, B, 4), block 256: wave g handles 16 channels.
// ---------------------------------------------------------------------------
__global__ __launch_bounds__(256) void proj_kernel(
    const float* __restrict__ Omrg, const float* __restrict__ ow,
    const float* __restrict__ x, float* __restrict__ y)
{
    const int b  = blockIdx.y;
    const int z  = blockIdx.z;
    const int nl = threadIdx.x & 63;
    const int n  = blockIdx.x * 64 + nl;
    const int g  = __builtin_amdgcn_readfirstlane(threadIdx.x >> 6);

    float o[CR];
#pragma unroll
    for (int r = 0; r < CR; ++r)
        o[r] = Omrg[((size_t)b * CR + r) * NPOS + n];

    const float* xb = x + (size_t)b * CIN * NPOS + n;
    float*       yb = y + (size_t)b * CIN * NPOS + n;
    const int c0 = z * 64 + g * 16;
#pragma unroll
    for (int cc = 0; cc < 16; ++cc) {
        int c = c0 + cc;                          // wave-uniform
        float acc = xb[(size_t)c * NPOS];
#pragma unroll
        for (int r = 0; r < CR; ++r) acc += ow[c * CR + r] * o[r];
        yb[(size_t)c * NPOS] = acc;
    }
}

// ---------------------------------------------------------------------------
extern "C" void kernel_launch(void* const* d_in, const int* in_sizes, int n_in,
                              void* d_out, int out_size, void* d_ws, size_t ws_size,
                              hipStream_t stream)
{
    const float* x  = (const float*)d_in[0];
    const float* qw = (const float*)d_in[1];
    const float* kw = (const float*)d_in[2];
    const float* vw = (const float*)d_in[3];
    const float* ow = (const float*)d_in[4];
    float* out = (float*)d_out;

    const size_t qkvN = (size_t)BATCH * CR * NPOS;   // 401,408 elements
    // S must divide 98 (=6272/64). S=7: halved Opart/M/L traffic (proven);
    // attn ITERS=14 stays on the fully-pipelined path.
    const int s_cand[4] = {7, 14, 2, 1};
    int S = 1;
    for (int i = 0; i < 4; ++i) {
        int Sc = s_cand[i];
        size_t need = 3 * qkvN * sizeof(ushort_t)            // Qf,Kf,Vt
                    + qkvN * sizeof(float)                   // Omrg
                    + (size_t)Sc * qkvN * sizeof(ushort_t)   // Opart
                    + 2 * (size_t)Sc * BATCH * NPOS * sizeof(float); // M,L
        if (need <= ws_size) { S = Sc; break; }
    }
    ushort_t* Qf = (ushort_t*)d_ws;
    ushort_t* Kf = Qf + qkvN;
    ushort_t* Vt = Kf + qkvN;
    float* Omrg  = (float*)(Vt + qkvN);
    ushort_t* Op = (ushort_t*)(Omrg + qkvN);
    float* Mp    = (float*)(Op + (size_t)S * qkvN);
    float* Lp    = Mp + (size_t)S * BATCH * NPOS;

    qkv_kernel<<<dim3(NT, BATCH, 3), 256, 0, stream>>>(x, qw, kw, vw,
                                                       Qf, Kf, Vt);
    dim3 ag(NT, S, BATCH);
    switch (S) {
        case 14: attn_kernel<7> <<<ag, 128, 0, stream>>>(Qf, Kf, Vt, Op, Mp, Lp); break;
        case 7:  attn_kernel<14><<<ag, 128, 0, stream>>>(Qf, Kf, Vt, Op, Mp, Lp); break;
        case 2:  attn_kernel<49><<<ag, 128, 0, stream>>>(Qf, Kf, Vt, Op, Mp, Lp); break;
        default: attn_kernel<98><<<ag, 128, 0, stream>>>(Qf, Kf, Vt, Op, Mp, Lp); break;
    }
    dim3 mg(NT, BATCH, 8);
    switch (S) {
        case 14: merge_kernel<14><<<mg, 256, 0, stream>>>(Op, Mp, Lp, Omrg); break;
        case 7:  merge_kernel<7> <<<mg, 256, 0, stream>>>(Op, Mp, Lp, Omrg); break;
        case 2:  merge_kernel<2> <<<mg, 256, 0, stream>>>(Op, Mp, Lp, Omrg); break;
        default: merge_kernel<1> <<<mg, 256, 0, stream>>>(Op, Mp, Lp, Omrg); break;
    }
    proj_kernel<<<dim3(NT, BATCH, 4), 256, 0, stream>>>(Omrg, ow, x, out);
}